// Round 1
// baseline (4411.872 us; speedup 1.0000x reference)
//
#include <hip/hip_runtime.h>

// NoMCOutModel: recurrent mass-redistribution scan.
// B=256 batches -> 1 workgroup (1024 thr = 16 waves) per batch, one per CU.
// Wave w owns R-rows {w, w+16, w+32, w+48}; lane l owns column k=l.
// Wr slice held in registers (128 VGPR/thread); softmax over k = wave shuffle
// reduction; row normalization folded into c[h]/S[h]; per-step cell update via
// one LDS atomicAdd per thread into a double-buffered c[64].

namespace {

constexpr int B_ = 256, T_ = 256, M_ = 8, AUX_ = 32, H_ = 64;

__device__ __forceinline__ float wave_sum64(float v) {
    v += __shfl_xor(v, 1);
    v += __shfl_xor(v, 2);
    v += __shfl_xor(v, 4);
    v += __shfl_xor(v, 8);
    v += __shfl_xor(v, 16);
    v += __shfl_xor(v, 32);
    return v;
}

__global__ __launch_bounds__(1024, 1)
void nomc_fused(const float* __restrict__ x_m, const float* __restrict__ x_a,
                const float* __restrict__ Wj, const float* __restrict__ bj,
                const float* __restrict__ Wr, const float* __restrict__ br,
                const float* __restrict__ Wo, const float* __restrict__ bo,
                const float* __restrict__ Wfc, const float* __restrict__ bfc,
                float* __restrict__ out)
{
    const int b   = blockIdx.x;
    const int tid = threadIdx.x;
    const int w   = tid >> 6;   // wave 0..15
    const int l   = tid & 63;   // lane 0..63

    __shared__ float c_buf[2][H_];

    // ---- preload Wr slice: rows h_i = w + 16*i, column l ----
    float wr[4][AUX_];
    float brv[4];
#pragma unroll
    for (int i = 0; i < 4; ++i) {
        const int h = w + 16 * i;
#pragma unroll
        for (int a = 0; a < AUX_; ++a)
            wr[i][a] = Wr[a * (H_ * H_) + h * H_ + l];  // coalesced over l
        brv[i] = br[h * H_ + l];
    }

    // ---- preload Wj slice for waves 0..7 (wave = junction row m) ----
    float wj[AUX_];
    float bjv = 0.f;
    if (w < M_) {
#pragma unroll
        for (int a = 0; a < AUX_; ++a)
            wj[a] = Wj[a * (M_ * H_) + w * H_ + l];
        bjv = bj[w * H_ + l];
    } else {
#pragma unroll
        for (int a = 0; a < AUX_; ++a) wj[a] = 0.f;
    }

    if (tid < H_) { c_buf[0][tid] = 0.f; c_buf[1][tid] = 0.f; }

    // ---- x_a double buffer (uniform address -> expect s_load into SGPRs) ----
    float xaA[AUX_], xaB[AUX_];
    {
        const float* xa0 = x_a + (size_t)b * T_ * AUX_;
#pragma unroll
        for (int a = 0; a < AUX_; ++a) xaA[a] = xa0[a];
    }
    __syncthreads();

    int cur = 0;

    auto step = [&](int t, float (&xv)[AUX_], float (&xn)[AUX_]) {
        // prefetch next timestep's aux input (latency hidden under FMA body)
        const int tn = (t + 1 < T_) ? (t + 1) : (T_ - 1);
        const float* xan = x_a + ((size_t)b * T_ + tn) * AUX_;
#pragma unroll
        for (int a = 0; a < AUX_; ++a) xn[a] = xan[a];

        const int nxt = cur ^ 1;
        float part = 0.f;

        // redistribution: 4 R-rows per wave
#pragma unroll
        for (int i = 0; i < 4; ++i) {
            float L = brv[i];
#pragma unroll
            for (int a = 0; a < AUX_; ++a) L = fmaf(xv[a], wr[i][a], L);
            const float e = __expf(L);             // logits ~N(0,0.34): no max-sub needed
            const float s = wave_sum64(e);         // row sum over 64 lanes
            const float ch = c_buf[cur][w + 16 * i];  // wave-uniform LDS broadcast
            part = fmaf(ch * __builtin_amdgcn_rcpf(s), e, part);
        }

        // junction inflow: waves 0..7, row m = w
        if (w < M_) {
            const float xmv = x_m[((size_t)b * T_ + t) * M_ + w];
            float L = bjv;
#pragma unroll
            for (int a = 0; a < AUX_; ++a) L = fmaf(xv[a], wj[a], L);
            const float e = __expf(L);
            const float s = wave_sum64(e);
            part = fmaf(xmv * __builtin_amdgcn_rcpf(s), e, part);
        }

        atomicAdd(&c_buf[nxt][l], part);           // 16 adds per cell, ds_add_f32
        __syncthreads();
        // c_buf[nxt] complete; recycle old buffer as next accumulator
        if (tid < H_) c_buf[cur][tid] = 0.f;
        __syncthreads();
        cur = nxt;
    };

    for (int t = 0; t < T_; t += 2) {
        step(t,     xaA, xaB);
        step(t + 1, xaB, xaA);
    }

    // ---- epilogue: out = (sigmoid(xa_last@Wo+bo) * c_T) @ Wfc + bfc ----
    if (w == 0) {
        const float* xa = x_a + ((size_t)b * T_ + (T_ - 1)) * AUX_;
        float L = bo[l];
#pragma unroll
        for (int a = 0; a < AUX_; ++a) L = fmaf(xa[a], Wo[a * H_ + l], L);
        const float o    = 1.0f / (1.0f + __expf(-L));
        const float cfin = c_buf[cur][l];
        float p = (o * cfin) * Wfc[l];
        p = wave_sum64(p);
        if (l == 0) out[b] = p + bfc[0];
        out[B_ + b * H_ + l] = cfin;               // c_final, coalesced
    }
}

} // namespace

extern "C" void kernel_launch(void* const* d_in, const int* in_sizes, int n_in,
                              void* d_out, int out_size, void* d_ws, size_t ws_size,
                              hipStream_t stream) {
    const float* x_m = (const float*)d_in[0];
    const float* x_a = (const float*)d_in[1];
    const float* Wj  = (const float*)d_in[2];
    const float* bj  = (const float*)d_in[3];
    const float* Wr  = (const float*)d_in[4];
    const float* br  = (const float*)d_in[5];
    const float* Wo  = (const float*)d_in[6];
    const float* bo  = (const float*)d_in[7];
    const float* Wfc = (const float*)d_in[8];
    const float* bfc = (const float*)d_in[9];
    float* out = (float*)d_out;

    hipLaunchKernelGGL(nomc_fused, dim3(B_), dim3(1024), 0, stream,
                       x_m, x_a, Wj, bj, Wr, br, Wo, bo, Wfc, bfc, out);
}

// Round 3
// 900.555 us; speedup vs baseline: 4.8991x; 4.8991x over previous
//
#include <hip/hip_runtime.h>

// NoMCOutModel: recurrent mass-redistribution scan, f16-packed weights.
// B=256 batches -> 1 workgroup (1024 thr = 16 waves) per batch, one per CU.
// Wave w owns R-rows {w,w+16,w+32,w+48}; lane l owns column k=l.
// Weights held as packed half2 in VGPRs (wr: 64 regs, wj: 16 regs); inner
// product via v_dot2_f32_f16 (fp32 accumulate). x_a is block-uniform ->
// compiler scalarizes into SGPRs (verified round 1: SGPR_Count=96).
// __launch_bounds__(1024,4): pin 4 waves/EU -> 128-VGPR cap, no spill
// (round 1 failure mode: compiler capped at 64 VGPRs and spilled wr to
// scratch -> 6.4 GB HBM traffic, 8% VALUBusy).
// half2_t must be the __fp16 ext-vector (round 2 failure: _Float16 vector is
// incompatible with __builtin_amdgcn_cvt_pkrtz / fdot2 signatures).

namespace {

constexpr int B_ = 256, T_ = 256, M_ = 8, AUX_ = 32, H_ = 64;
constexpr int AH_ = AUX_ / 2;  // 16 half2 per 32-length dot

typedef __fp16 half2_t __attribute__((ext_vector_type(2)));

__device__ __forceinline__ float wave_sum64(float v) {
    v += __shfl_xor(v, 1);
    v += __shfl_xor(v, 2);
    v += __shfl_xor(v, 4);
    v += __shfl_xor(v, 8);
    v += __shfl_xor(v, 16);
    v += __shfl_xor(v, 32);
    return v;
}

__global__ __launch_bounds__(1024, 4)
void nomc_fused(const float* __restrict__ x_m, const float* __restrict__ x_a,
                const float* __restrict__ Wj, const float* __restrict__ bj,
                const float* __restrict__ Wr, const float* __restrict__ br,
                const float* __restrict__ Wo, const float* __restrict__ bo,
                const float* __restrict__ Wfc, const float* __restrict__ bfc,
                float* __restrict__ out)
{
    const int b   = blockIdx.x;
    const int tid = threadIdx.x;
    const int w   = tid >> 6;   // wave 0..15
    const int l   = tid & 63;   // lane 0..63

    __shared__ float c_buf[2][H_];

    // ---- preload Wr slice as packed half2: rows h_i = w + 16*i, column l ----
    half2_t wr[4][AH_];
    float brv[4];
#pragma unroll
    for (int i = 0; i < 4; ++i) {
        const int h = w + 16 * i;
#pragma unroll
        for (int j = 0; j < AH_; ++j) {
            const float f0 = Wr[(2 * j)     * (H_ * H_) + h * H_ + l];  // coalesced over l
            const float f1 = Wr[(2 * j + 1) * (H_ * H_) + h * H_ + l];
            wr[i][j] = __builtin_amdgcn_cvt_pkrtz(f0, f1);
        }
        brv[i] = br[h * H_ + l];
    }

    // ---- preload Wj slice (waves 0..7; wave = junction row m) ----
    half2_t wj[AH_];
    float bjv = 0.f;
    if (w < M_) {
#pragma unroll
        for (int j = 0; j < AH_; ++j) {
            const float f0 = Wj[(2 * j)     * (M_ * H_) + w * H_ + l];
            const float f1 = Wj[(2 * j + 1) * (M_ * H_) + w * H_ + l];
            wj[j] = __builtin_amdgcn_cvt_pkrtz(f0, f1);
        }
        bjv = bj[w * H_ + l];
    } else {
#pragma unroll
        for (int j = 0; j < AH_; ++j) wj[j] = half2_t{(__fp16)0.f, (__fp16)0.f};
    }

    if (tid < H_) { c_buf[0][tid] = 0.f; c_buf[1][tid] = 0.f; }

    // ---- x_a double buffer: uniform addresses -> SGPRs (s_load) ----
    float xaA[AUX_], xaB[AUX_];
    {
        const float* xa0 = x_a + (size_t)b * T_ * AUX_;
#pragma unroll
        for (int a = 0; a < AUX_; ++a) xaA[a] = xa0[a];
    }
    __syncthreads();

    int cur = 0;

#define STEP(T0, XV, XN)                                                      \
    {                                                                         \
        const int tn = ((T0) + 1 < T_) ? ((T0) + 1) : (T_ - 1);               \
        const float* xan = x_a + ((size_t)b * T_ + tn) * AUX_;                \
        _Pragma("unroll")                                                     \
        for (int a = 0; a < AUX_; ++a) XN[a] = xan[a];                        \
        half2_t xh[AH_];                                                      \
        _Pragma("unroll")                                                     \
        for (int j = 0; j < AH_; ++j)                                         \
            xh[j] = __builtin_amdgcn_cvt_pkrtz(XV[2 * j], XV[2 * j + 1]);     \
        const int nxt = cur ^ 1;                                              \
        float part = 0.f;                                                     \
        _Pragma("unroll")                                                     \
        for (int i = 0; i < 4; ++i) {                                         \
            float L = brv[i];                                                 \
            _Pragma("unroll")                                                 \
            for (int j = 0; j < AH_; ++j)                                     \
                L = __builtin_amdgcn_fdot2(xh[j], wr[i][j], L, false);        \
            const float e = __expf(L);                                        \
            const float s = wave_sum64(e);                                    \
            const float ch = c_buf[cur][w + 16 * i];                          \
            part = fmaf(ch * __builtin_amdgcn_rcpf(s), e, part);              \
        }                                                                     \
        if (w < M_) {                                                         \
            const float xmv = x_m[((size_t)b * T_ + (T0)) * M_ + w];          \
            float L = bjv;                                                    \
            _Pragma("unroll")                                                 \
            for (int j = 0; j < AH_; ++j)                                     \
                L = __builtin_amdgcn_fdot2(xh[j], wj[j], L, false);           \
            const float e = __expf(L);                                        \
            const float s = wave_sum64(e);                                    \
            part = fmaf(xmv * __builtin_amdgcn_rcpf(s), e, part);             \
        }                                                                     \
        atomicAdd(&c_buf[nxt][l], part);                                      \
        __syncthreads();                                                      \
        if (tid < H_) c_buf[cur][tid] = 0.f;                                  \
        __syncthreads();                                                      \
        cur = nxt;                                                            \
    }

    for (int t = 0; t < T_; t += 2) {
        STEP(t,     xaA, xaB);
        STEP(t + 1, xaB, xaA);
    }
#undef STEP

    // ---- epilogue: out = (sigmoid(xa_last@Wo+bo) * c_T) @ Wfc + bfc ----
    if (w == 0) {
        const float* xa = x_a + ((size_t)b * T_ + (T_ - 1)) * AUX_;
        float L = bo[l];
#pragma unroll
        for (int a = 0; a < AUX_; ++a) L = fmaf(xa[a], Wo[a * H_ + l], L);
        const float o    = 1.0f / (1.0f + __expf(-L));
        const float cfin = c_buf[cur][l];
        float p = (o * cfin) * Wfc[l];
        p = wave_sum64(p);
        if (l == 0) out[b] = p + bfc[0];
        out[B_ + b * H_ + l] = cfin;               // c_final, coalesced
    }
}

} // namespace

extern "C" void kernel_launch(void* const* d_in, const int* in_sizes, int n_in,
                              void* d_out, int out_size, void* d_ws, size_t ws_size,
                              hipStream_t stream) {
    const float* x_m = (const float*)d_in[0];
    const float* x_a = (const float*)d_in[1];
    const float* Wj  = (const float*)d_in[2];
    const float* bj  = (const float*)d_in[3];
    const float* Wr  = (const float*)d_in[4];
    const float* br  = (const float*)d_in[5];
    const float* Wo  = (const float*)d_in[6];
    const float* bo  = (const float*)d_in[7];
    const float* Wfc = (const float*)d_in[8];
    const float* bfc = (const float*)d_in[9];
    float* out = (float*)d_out;

    hipLaunchKernelGGL(nomc_fused, dim3(B_), dim3(1024), 0, stream,
                       x_m, x_a, Wj, bj, Wr, br, Wo, bo, Wfc, bfc, out);
}

// Round 4
// 453.756 us; speedup vs baseline: 9.7230x; 1.9847x over previous
//
#include <hip/hip_runtime.h>

// NoMCOutModel: recurrent mass-redistribution scan, round 4.
// 1 WG (1024 thr = 16 waves) per batch element, 1 per CU. Wave w owns R-rows
// {w,w+16,w+32,w+48}; lane l = column k. f16-packed weights in VGPRs (fdot2,
// fp32 acc), log2e pre-folded so softmax uses raw v_exp_f32.
//
// Round-3 post-mortem: 880us, VALUBusy 34% -> latency-bound on per-step
// serial chain (6x ds_swizzle shuffle reduce, LDS atomicAdd, 2 barriers).
// This round: DPP-based reductions (VALU, ~2-4cyc vs ~40cyc LDS swizzle),
// partial-staging c-update (ds_write + ONE barrier + DPP group-reduce;
// no atomics, no zero pass), software-pipelined so step t+1's dot/exp block
// fills the post-barrier reduce latency, x_m pre-staged in LDS.

namespace {

constexpr int B_ = 256, T_ = 256, M_ = 8, AUX_ = 32, H_ = 64;
constexpr int AH_ = AUX_ / 2;   // 16 half2 per 32-dot
constexpr int CP_ = H_ + 1;     // cpart row pad -> worst 2-way bank alias (free)
constexpr float LOG2E_ = 1.4426950408889634f;

typedef __fp16 half2_t __attribute__((ext_vector_type(2)));

#if __has_builtin(__builtin_amdgcn_exp2f)
#define EXP2(x) __builtin_amdgcn_exp2f(x)
#else
#define EXP2(x) exp2f(x)
#endif

template <int CTRL>
__device__ __forceinline__ float dpp_add(float v) {
    int t = __builtin_amdgcn_update_dpp(0, __builtin_bit_cast(int, v),
                                        CTRL, 0xf, 0xf, true);
    return v + __builtin_bit_cast(float, t);
}

// sum over all 64 lanes -> wave-uniform (SGPR) value.
// GPUOpen chain: row_shr 1,2,4,8 then row_bcast15, row_bcast31; total in lane 63.
__device__ __forceinline__ float sum64_uni(float v) {
    v = dpp_add<0x111>(v);
    v = dpp_add<0x112>(v);
    v = dpp_add<0x114>(v);
    v = dpp_add<0x118>(v);
    v = dpp_add<0x142>(v);
    v = dpp_add<0x143>(v);
    return __builtin_bit_cast(float,
        __builtin_amdgcn_readlane(__builtin_bit_cast(int, v), 63));
}

// sum within each 16-lane group, result in every lane of the group
// (mirror-style steps: quad_perm xor1, quad_perm xor2, half_mirror, mirror).
__device__ __forceinline__ float sum16_all(float v) {
    v = dpp_add<0xB1>(v);
    v = dpp_add<0x4E>(v);
    v = dpp_add<0x141>(v);
    v = dpp_add<0x140>(v);
    return v;
}

__device__ __forceinline__ float rl(float v, int lane) {
    return __builtin_bit_cast(float,
        __builtin_amdgcn_readlane(__builtin_bit_cast(int, v), lane));
}

__global__ __launch_bounds__(1024, 4)
void nomc_fused(const float* __restrict__ x_m, const float* __restrict__ x_a,
                const float* __restrict__ Wj, const float* __restrict__ bj,
                const float* __restrict__ Wr, const float* __restrict__ br,
                const float* __restrict__ Wo, const float* __restrict__ bo,
                const float* __restrict__ Wfc, const float* __restrict__ bfc,
                float* __restrict__ out)
{
    const int b   = blockIdx.x;
    const int tid = threadIdx.x;
    const int w   = tid >> 6;   // wave 0..15
    const int l   = tid & 63;   // lane 0..63
    const int g   = l >> 4;     // 16-lane group 0..3 (R-row index within wave)

    __shared__ float cpart[2][16][CP_];   // per-wave c partials, double-buffered
    __shared__ float xm_lds[T_][M_];      // whole-batch x_m staged once
    __shared__ float cfin_lds[H_];

    // ---- preload weights (f16-packed, log2e folded), coalesced over l ----
    half2_t wr[4][AH_];
    float brv[4];
#pragma unroll
    for (int i = 0; i < 4; ++i) {
        const int h = w + 16 * i;
#pragma unroll
        for (int j = 0; j < AH_; ++j) {
            const float f0 = Wr[(2 * j)     * (H_ * H_) + h * H_ + l] * LOG2E_;
            const float f1 = Wr[(2 * j + 1) * (H_ * H_) + h * H_ + l] * LOG2E_;
            wr[i][j] = __builtin_amdgcn_cvt_pkrtz(f0, f1);
        }
        brv[i] = br[h * H_ + l] * LOG2E_;
    }
    half2_t wj[AH_];
    float bjv = 0.f;
    if (w < M_) {
#pragma unroll
        for (int j = 0; j < AH_; ++j) {
            const float f0 = Wj[(2 * j)     * (M_ * H_) + w * H_ + l] * LOG2E_;
            const float f1 = Wj[(2 * j + 1) * (M_ * H_) + w * H_ + l] * LOG2E_;
            wj[j] = __builtin_amdgcn_cvt_pkrtz(f0, f1);
        }
        bjv = bj[w * H_ + l] * LOG2E_;
    } else {
#pragma unroll
        for (int j = 0; j < AH_; ++j) wj[j] = half2_t{(__fp16)0.f, (__fp16)0.f};
    }

    // ---- stage x_m; zero cpart[0] (= c_0) ----
    {
        const float* xmb = x_m + (size_t)b * T_ * M_;
        float* xd = &xm_lds[0][0];
        for (int i = tid; i < T_ * M_; i += 1024) xd[i] = xmb[i];
        float* cz = &cpart[0][0][0];
        for (int i = tid; i < 16 * CP_; i += 1024) cz[i] = 0.f;
    }
    __syncthreads();

    // e_norm for step t: en[i] = e_i/s_i (4 R-rows); jn = xm * e_j/s_j
#define COMPUTE_EN(X, XMV, EN, JN)                                            \
    {                                                                         \
        half2_t xh[AH_];                                                      \
        _Pragma("unroll")                                                     \
        for (int j = 0; j < AH_; ++j)                                         \
            xh[j] = __builtin_amdgcn_cvt_pkrtz((X)[2 * j], (X)[2 * j + 1]);   \
        _Pragma("unroll")                                                     \
        for (int i = 0; i < 4; ++i) {                                         \
            float L = brv[i];                                                 \
            _Pragma("unroll")                                                 \
            for (int j = 0; j < AH_; ++j)                                     \
                L = __builtin_amdgcn_fdot2(xh[j], wr[i][j], L, false);        \
            const float e = EXP2(L);                                          \
            const float s = sum64_uni(e);                                     \
            (EN)[i] = e * __builtin_amdgcn_rcpf(s);                           \
        }                                                                     \
        (JN) = 0.f;                                                           \
        if (w < M_) {                                                         \
            float L = bjv;                                                    \
            _Pragma("unroll")                                                 \
            for (int j = 0; j < AH_; ++j)                                     \
                L = __builtin_amdgcn_fdot2(xh[j], wj[j], L, false);           \
            const float e = EXP2(L);                                          \
            const float s = sum64_uni(e);                                     \
            (JN) = e * ((XMV) * __builtin_amdgcn_rcpf(s));                    \
        }                                                                     \
    }

    // ---- x_a double buffer (block-uniform -> SGPRs) + en(0) ----
    float xaS0[AUX_], xaS1[AUX_];
    {
        const float* p = x_a + (size_t)b * T_ * AUX_;
#pragma unroll
        for (int a = 0; a < AUX_; ++a) xaS0[a] = p[a];
    }
    float enA[4], jnA, enB[4], jnB;
    {
        const float xm0 = xm_lds[0][w & 7];
        COMPUTE_EN(xaS0, xm0, enA, jnA);
        const float* p = x_a + ((size_t)b * T_ + 1) * AUX_;
#pragma unroll
        for (int a = 0; a < AUX_; ++a) xaS1[a] = p[a];
    }

    // Iter t: reads cpart[P] (c_t partials), consumes EN_C (step t), writes
    // cpart[P^1] (c_{t+1} partials), computes EN_N (step t+1) from XU
    // (= xa[t+1]), prefetches xa[t+2] into XP. ONE barrier per step.
#define ITER(T0, P, EN_C, JN_C, EN_N, JN_N, XU, XP)                           \
    {                                                                         \
        const float cv = cpart[P][l & 15][(g << 4) + w];                      \
        const int tn = ((T0) + 1 < T_) ? (T0) + 1 : T_ - 1;                   \
        const float xm_n = xm_lds[tn][w & 7];                                 \
        const float red = sum16_all(cv);                                      \
        float part =     rl(red, 0)  * (EN_C)[0];                             \
        part = fmaf(rl(red, 16), (EN_C)[1], part);                            \
        part = fmaf(rl(red, 32), (EN_C)[2], part);                            \
        part = fmaf(rl(red, 48), (EN_C)[3], part);                            \
        if (w < M_) part += (JN_C);                                           \
        cpart[P ^ 1][w][l] = part;                                            \
        COMPUTE_EN(XU, xm_n, EN_N, JN_N);                                     \
        const int tp = ((T0) + 2 < T_) ? (T0) + 2 : T_ - 1;                   \
        const float* xap = x_a + ((size_t)b * T_ + tp) * AUX_;                \
        _Pragma("unroll")                                                     \
        for (int a = 0; a < AUX_; ++a) (XP)[a] = xap[a];                      \
        __syncthreads();                                                      \
    }

    for (int t = 0; t < T_; t += 2) {
        ITER(t,     0, enA, jnA, enB, jnB, xaS1, xaS0);
        ITER(t + 1, 1, enB, jnB, enA, jnA, xaS0, xaS1);
    }
#undef ITER
#undef COMPUTE_EN

    // ---- c_final = reduce(cpart[0]) ----
    {
        const float cv = cpart[0][l & 15][(g << 4) + w];
        const float red = sum16_all(cv);
        if ((l & 15) == 0) cfin_lds[w + (g << 4)] = red;
    }
    __syncthreads();

    // ---- epilogue: out = (sigmoid(xa_T @ Wo + bo) * c_T) @ Wfc + bfc ----
    if (w == 0) {
        const float* xa = x_a + ((size_t)b * T_ + (T_ - 1)) * AUX_;
        float L = bo[l];
#pragma unroll
        for (int a = 0; a < AUX_; ++a) L = fmaf(xa[a], Wo[a * H_ + l], L);
        const float o    = 1.0f / (1.0f + __expf(-L));
        const float cfin = cfin_lds[l];
        float p = (o * cfin) * Wfc[l];
        p = sum64_uni(p);
        if (l == 0) out[b] = p + bfc[0];
        out[B_ + b * H_ + l] = cfin;   // c_final, coalesced
    }
}

} // namespace

extern "C" void kernel_launch(void* const* d_in, const int* in_sizes, int n_in,
                              void* d_out, int out_size, void* d_ws, size_t ws_size,
                              hipStream_t stream) {
    const float* x_m = (const float*)d_in[0];
    const float* x_a = (const float*)d_in[1];
    const float* Wj  = (const float*)d_in[2];
    const float* bj  = (const float*)d_in[3];
    const float* Wr  = (const float*)d_in[4];
    const float* br  = (const float*)d_in[5];
    const float* Wo  = (const float*)d_in[6];
    const float* bo  = (const float*)d_in[7];
    const float* Wfc = (const float*)d_in[8];
    const float* bfc = (const float*)d_in[9];
    float* out = (float*)d_out;

    hipLaunchKernelGGL(nomc_fused, dim3(B_), dim3(1024), 0, stream,
                       x_m, x_a, Wj, bj, Wr, br, Wo, bo, Wfc, bfc, out);
}